// Round 1
// baseline (835.974 us; speedup 1.0000x reference)
//
#include <hip/hip_runtime.h>
#include <cmath>

#define TS 2048   // sequence
#define TH 768    // hidden
#define TNH 12    // heads
#define THD 64    // head dim
#define TNF 128   // rff features

// ---------------- wave helpers (wave = 64) ----------------
__device__ __forceinline__ float waveReduceSum(float v) {
#pragma unroll
    for (int off = 32; off >= 1; off >>= 1) v += __shfl_xor(v, off, 64);
    return v;
}
__device__ __forceinline__ float waveReduceMax(float v) {
#pragma unroll
    for (int off = 32; off >= 1; off >>= 1) v = fmaxf(v, __shfl_xor(v, off, 64));
    return v;
}

// ---------------- inner-product microkernel ----------------
// As/Bs stored transposed: [k up to 32][64 + pad], stride 68 floats so the
// float4 LDS reads stay 16B-aligned (68*4B = 272B multiple of 16).
__device__ __forceinline__ void fma16(float (&acc)[4][4], const float* pa, const float* pb) {
#pragma unroll
    for (int kk = 0; kk < 32; ++kk) {
        float4 a = *(const float4*)(pa + kk * 68);
        float4 b = *(const float4*)(pb + kk * 68);
        float av[4] = {a.x, a.y, a.z, a.w};
        float bv[4] = {b.x, b.y, b.z, b.w};
#pragma unroll
        for (int i = 0; i < 4; ++i)
#pragma unroll
            for (int j = 0; j < 4; ++j) acc[i][j] += av[i] * bv[j];
    }
}

// ---------------- QKV projection: Y = X @ W^T + b, scatter to (h,s,d) ----------------
__global__ __launch_bounds__(256) void k_proj_qkv(
    const float* __restrict__ X,
    const float* __restrict__ W0, const float* __restrict__ b0,
    const float* __restrict__ W1, const float* __restrict__ b1,
    const float* __restrict__ W2, const float* __restrict__ b2,
    float* __restrict__ dq, float* __restrict__ dk, float* __restrict__ dv) {
    __shared__ float As[32][68];
    __shared__ float Bs[32][68];
    const int z = blockIdx.z;
    const float* W = (z == 0) ? W0 : ((z == 1) ? W1 : W2);
    const float* bias = (z == 0) ? b0 : ((z == 1) ? b1 : b2);
    float* dst = (z == 0) ? dq : ((z == 1) ? dk : dv);
    const int n0 = blockIdx.x * 64;
    const int m0 = blockIdx.y * 64;
    const int tid = threadIdx.x;
    float acc[4][4] = {};
    for (int k0 = 0; k0 < TH; k0 += 32) {
#pragma unroll
        for (int l = 0; l < 2; ++l) {
            int i = tid + l * 256;
            int row = i >> 3, col = (i & 7) << 2;
            float4 a = *(const float4*)&X[(m0 + row) * TH + k0 + col];
            As[col + 0][row] = a.x; As[col + 1][row] = a.y;
            As[col + 2][row] = a.z; As[col + 3][row] = a.w;
            float4 b = *(const float4*)&W[(n0 + row) * TH + k0 + col];
            Bs[col + 0][row] = b.x; Bs[col + 1][row] = b.y;
            Bs[col + 2][row] = b.z; Bs[col + 3][row] = b.w;
        }
        __syncthreads();
        fma16(acc, &As[0][0] + ((tid >> 4) << 2), &Bs[0][0] + ((tid & 15) << 2));
        __syncthreads();
    }
    const int mb = m0 + ((tid >> 4) << 2);
    const int nb = n0 + ((tid & 15) << 2);
#pragma unroll
    for (int i = 0; i < 4; ++i)
#pragma unroll
        for (int j = 0; j < 4; ++j) {
            int n = nb + j;
            float val = acc[i][j] + bias[n];
            int h = n >> 6, d = n & 63;
            dst[(h * TS + (mb + i)) * THD + d] = val;
        }
}

// ---------------- output projection: out = ctx @ Wo^T + bo ----------------
__global__ __launch_bounds__(256) void k_proj_out(
    const float* __restrict__ X, const float* __restrict__ W,
    const float* __restrict__ bias, float* __restrict__ out) {
    __shared__ float As[32][68];
    __shared__ float Bs[32][68];
    const int n0 = blockIdx.x * 64;
    const int m0 = blockIdx.y * 64;
    const int tid = threadIdx.x;
    float acc[4][4] = {};
    for (int k0 = 0; k0 < TH; k0 += 32) {
#pragma unroll
        for (int l = 0; l < 2; ++l) {
            int i = tid + l * 256;
            int row = i >> 3, col = (i & 7) << 2;
            float4 a = *(const float4*)&X[(m0 + row) * TH + k0 + col];
            As[col + 0][row] = a.x; As[col + 1][row] = a.y;
            As[col + 2][row] = a.z; As[col + 3][row] = a.w;
            float4 b = *(const float4*)&W[(n0 + row) * TH + k0 + col];
            Bs[col + 0][row] = b.x; Bs[col + 1][row] = b.y;
            Bs[col + 2][row] = b.z; Bs[col + 3][row] = b.w;
        }
        __syncthreads();
        fma16(acc, &As[0][0] + ((tid >> 4) << 2), &Bs[0][0] + ((tid & 15) << 2));
        __syncthreads();
    }
    const int mb = m0 + ((tid >> 4) << 2);
    const int nb = n0 + ((tid & 15) << 2);
#pragma unroll
    for (int i = 0; i < 4; ++i)
#pragma unroll
        for (int j = 0; j < 4; ++j) {
            int n = nb + j;
            out[(mb + i) * TH + n] = acc[i][j] + bias[n];
        }
}

// ---------------- row inverse norms for q,k (64 threads = 1 wave / row) ----------------
__global__ __launch_bounds__(64) void k_rownorm(
    const float* __restrict__ q, const float* __restrict__ kbuf,
    float* __restrict__ invq, float* __restrict__ invk) {
    const int row = blockIdx.x;
    const float* src = blockIdx.y ? kbuf : q;
    float* dst = blockIdx.y ? invk : invq;
    float x = src[row * THD + threadIdx.x];
    float ss = waveReduceSum(x * x);
    if (threadIdx.x == 0) dst[row] = 1.0f / (sqrtf(ss) + 1e-5f);
}

// ---------------- phi GEMM: Z = (x * inv) @ omega[h]^T, p = 0.125*cos(Z + b) ----------------
__global__ __launch_bounds__(256) void k_phi(
    const float* __restrict__ q, const float* __restrict__ kbuf,
    const float* __restrict__ invq, const float* __restrict__ invk,
    const float* __restrict__ omega, const float* __restrict__ rffb,
    float* __restrict__ pq, float* __restrict__ pk) {
    __shared__ float As[32][68];
    __shared__ float Bs[32][68];
    const int z = blockIdx.z;
    const int h = z >> 1, which = z & 1;
    const float* X = which ? kbuf : q;
    const float* inv = which ? invk : invq;
    float* dst = which ? pk : pq;
    const int n0 = blockIdx.x * 64;
    const int m0 = blockIdx.y * 64;
    const int tid = threadIdx.x;
    float acc[4][4] = {};
    for (int k0 = 0; k0 < THD; k0 += 32) {
#pragma unroll
        for (int l = 0; l < 2; ++l) {
            int i = tid + l * 256;
            int row = i >> 3, col = (i & 7) << 2;
            int rq = h * TS + m0 + row;
            float s = inv[rq];
            float4 a = *(const float4*)&X[rq * THD + k0 + col];
            As[col + 0][row] = a.x * s; As[col + 1][row] = a.y * s;
            As[col + 2][row] = a.z * s; As[col + 3][row] = a.w * s;
            float4 b = *(const float4*)&omega[(h * TNF + n0 + row) * THD + k0 + col];
            Bs[col + 0][row] = b.x; Bs[col + 1][row] = b.y;
            Bs[col + 2][row] = b.z; Bs[col + 3][row] = b.w;
        }
        __syncthreads();
        fma16(acc, &As[0][0] + ((tid >> 4) << 2), &Bs[0][0] + ((tid & 15) << 2));
        __syncthreads();
    }
    const int mb = m0 + ((tid >> 4) << 2);
    const int nb = n0 + ((tid & 15) << 2);
#pragma unroll
    for (int i = 0; i < 4; ++i)
#pragma unroll
        for (int j = 0; j < 4; ++j) {
            int f = nb + j;
            float zv = acc[i][j] + rffb[h * TNF + f];   // SIGMA = 1
            dst[(h * TS + (mb + i)) * TNF + f] = 0.125f * __cosf(zv) * 0.0f + 0.125f * cosf(zv);
        }
}

// ---------------- phi row L2-normalize; fold (1-alpha)=0.1 into phi_q ----------------
__global__ __launch_bounds__(128) void k_phinorm(float* __restrict__ pq, float* __restrict__ pk) {
    const int row = blockIdx.x;
    float* buf = blockIdx.y ? pk : pq;
    const float scale0 = blockIdx.y ? 1.0f : 0.1f;
    const int tid = threadIdx.x;
    float p = buf[row * TNF + tid];
    float ss = waveReduceSum(p * p);
    __shared__ float sh[2];
    if ((tid & 63) == 0) sh[tid >> 6] = ss;
    __syncthreads();
    ss = sh[0] + sh[1];
    float sc = scale0 / (sqrtf(ss) + 1e-6f);
    buf[row * TNF + tid] = p * sc;
}

// ---------------- scores: concat-K GEMM (K = 64 dot + 128 rff = 192) ----------------
__global__ __launch_bounds__(256) void k_scores(
    const float* __restrict__ q, const float* __restrict__ kbuf,
    const float* __restrict__ pq, const float* __restrict__ pk,
    const float* __restrict__ mask, float* __restrict__ wout) {
    __shared__ float As[32][68];
    __shared__ float Bs[32][68];
    const int h = blockIdx.z;
    const int n0 = blockIdx.x * 64;
    const int m0 = blockIdx.y * 64;
    const int tid = threadIdx.x;
    float acc[4][4] = {};
    for (int k0 = 0; k0 < 192; k0 += 32) {
#pragma unroll
        for (int l = 0; l < 2; ++l) {
            int i = tid + l * 256;
            int row = i >> 3, col = (i & 7) << 2;
            float4 a, b;
            if (k0 < 64) {
                a = *(const float4*)&q[(h * TS + m0 + row) * THD + k0 + col];
                a.x *= 0.1125f; a.y *= 0.1125f; a.z *= 0.1125f; a.w *= 0.1125f;  // alpha/sqrt(HD)
                b = *(const float4*)&kbuf[(h * TS + n0 + row) * THD + k0 + col];
            } else {
                a = *(const float4*)&pq[(h * TS + m0 + row) * TNF + (k0 - 64) + col];  // 0.1 folded
                b = *(const float4*)&pk[(h * TS + n0 + row) * TNF + (k0 - 64) + col];
            }
            As[col + 0][row] = a.x; As[col + 1][row] = a.y;
            As[col + 2][row] = a.z; As[col + 3][row] = a.w;
            Bs[col + 0][row] = b.x; Bs[col + 1][row] = b.y;
            Bs[col + 2][row] = b.z; Bs[col + 3][row] = b.w;
        }
        __syncthreads();
        fma16(acc, &As[0][0] + ((tid >> 4) << 2), &Bs[0][0] + ((tid & 15) << 2));
        __syncthreads();
    }
    const int mb = m0 + ((tid >> 4) << 2);
    const int nb = n0 + ((tid & 15) << 2);
#pragma unroll
    for (int i = 0; i < 4; ++i)
#pragma unroll
        for (int j = 0; j < 4; ++j) {
            int t = nb + j;
            wout[(h * TS + (mb + i)) * TS + t] = acc[i][j] + (mask[t] - 1.0f) * 10000.0f;
        }
}

// ---------------- softmax over rows of 2048, in place ----------------
__global__ __launch_bounds__(256) void k_softmax(float* __restrict__ wout) {
    const int row = blockIdx.x;
    float4* p = (float4*)(wout + (size_t)row * TS);
    const int tid = threadIdx.x;
    float4 x0 = p[tid], x1 = p[tid + 256];
    float mx = fmaxf(fmaxf(fmaxf(x0.x, x0.y), fmaxf(x0.z, x0.w)),
                     fmaxf(fmaxf(x1.x, x1.y), fmaxf(x1.z, x1.w)));
    mx = waveReduceMax(mx);
    __shared__ float rm[4];
    __shared__ float rs[4];
    if ((tid & 63) == 0) rm[tid >> 6] = mx;
    __syncthreads();
    mx = fmaxf(fmaxf(rm[0], rm[1]), fmaxf(rm[2], rm[3]));
    float e[8];
    e[0] = __expf(x0.x - mx); e[1] = __expf(x0.y - mx);
    e[2] = __expf(x0.z - mx); e[3] = __expf(x0.w - mx);
    e[4] = __expf(x1.x - mx); e[5] = __expf(x1.y - mx);
    e[6] = __expf(x1.z - mx); e[7] = __expf(x1.w - mx);
    float sum = ((e[0] + e[1]) + (e[2] + e[3])) + ((e[4] + e[5]) + (e[6] + e[7]));
    sum = waveReduceSum(sum);
    if ((tid & 63) == 0) rs[tid >> 6] = sum;
    __syncthreads();
    sum = rs[0] + rs[1] + rs[2] + rs[3];
    float rinv = 1.0f / sum;
    x0.x = e[0] * rinv; x0.y = e[1] * rinv; x0.z = e[2] * rinv; x0.w = e[3] * rinv;
    x1.x = e[4] * rinv; x1.y = e[5] * rinv; x1.z = e[6] * rinv; x1.w = e[7] * rinv;
    p[tid] = x0;
    p[tid + 256] = x1;
}

// ---------------- context GEMM: ctx[s, h*64+d] = sum_t w[h,s,t] * v[h,t,d] ----------------
__global__ __launch_bounds__(256) void k_ctx(
    const float* __restrict__ wout, const float* __restrict__ v, float* __restrict__ ctx) {
    __shared__ float As[32][68];
    __shared__ float Bs[32][68];
    const int h = blockIdx.y;
    const int m0 = blockIdx.x * 64;
    const int tid = threadIdx.x;
    float acc[4][4] = {};
    for (int k0 = 0; k0 < TS; k0 += 32) {
#pragma unroll
        for (int l = 0; l < 2; ++l) {
            int i = tid + l * 256;
            {
                int row = i >> 3, col = (i & 7) << 2;
                float4 a = *(const float4*)&wout[(size_t)(h * TS + m0 + row) * TS + k0 + col];
                As[col + 0][row] = a.x; As[col + 1][row] = a.y;
                As[col + 2][row] = a.z; As[col + 3][row] = a.w;
            }
            {
                int row = i >> 4, col = (i & 15) << 2;
                float4 b = *(const float4*)&v[(h * TS + k0 + row) * THD + col];
                *(float4*)&Bs[row][col] = b;
            }
        }
        __syncthreads();
        fma16(acc, &As[0][0] + ((tid >> 4) << 2), &Bs[0][0] + ((tid & 15) << 2));
        __syncthreads();
    }
    const int mb = m0 + ((tid >> 4) << 2);
    const int nb = (tid & 15) << 2;
#pragma unroll
    for (int i = 0; i < 4; ++i)
#pragma unroll
        for (int j = 0; j < 4; ++j) {
            ctx[(mb + i) * TH + h * THD + (nb + j)] = acc[i][j];
        }
}

extern "C" void kernel_launch(void* const* d_in, const int* in_sizes, int n_in,
                              void* d_out, int out_size, void* d_ws, size_t ws_size,
                              hipStream_t stream) {
    const float* hs    = (const float*)d_in[0];
    const float* mask  = (const float*)d_in[1];
    const float* Wq    = (const float*)d_in[2];
    const float* bq    = (const float*)d_in[3];
    const float* Wk    = (const float*)d_in[4];
    const float* bk    = (const float*)d_in[5];
    const float* Wv    = (const float*)d_in[6];
    const float* bv    = (const float*)d_in[7];
    const float* Wo    = (const float*)d_in[8];
    const float* bo    = (const float*)d_in[9];
    const float* omega = (const float*)d_in[10];
    const float* rffb  = (const float*)d_in[11];

    float* out0 = (float*)d_out;               // (S,H) final output
    float* wout = out0 + TS * TH;              // (NH,S,S) attention weights

    // workspace layout (floats); total ~12.63M floats = ~48.2 MB
    float* ws   = (float*)d_ws;
    float* q    = ws;                          // NH*S*HD = 1572864
    float* kbuf = ws + 1572864;
    float* v    = ws + 3145728;
    float* invq = ws + 4718592;                // NH*S = 24576
    float* invk = ws + 4743168;
    float* pq   = ws + 4767744;                // NH*S*NF = 3145728
    float* pk   = ws + 7913472;
    float* ctx  = ws + 11059200;               // S*H = 1572864

    k_proj_qkv<<<dim3(12, 32, 3), 256, 0, stream>>>(hs, Wq, bq, Wk, bk, Wv, bv, q, kbuf, v);
    k_rownorm<<<dim3(TNH * TS, 2), 64, 0, stream>>>(q, kbuf, invq, invk);
    k_phi<<<dim3(2, 32, 24), 256, 0, stream>>>(q, kbuf, invq, invk, omega, rffb, pq, pk);
    k_phinorm<<<dim3(TNH * TS, 2), 128, 0, stream>>>(pq, pk);
    k_scores<<<dim3(32, 32, 12), 256, 0, stream>>>(q, kbuf, pq, pk, mask, wout);
    k_softmax<<<TNH * TS, 256, 0, stream>>>(wout);
    k_ctx<<<dim3(32, 12), 256, 0, stream>>>(wout, v, ctx);
    k_proj_out<<<dim3(12, 32), 256, 0, stream>>>(ctx, Wo, bo, out0);
}

// Round 5
// 647.602 us; speedup vs baseline: 1.2909x; 1.2909x over previous
//
#include <hip/hip_runtime.h>
#include <cmath>

#define TS 2048   // sequence
#define TH 768    // hidden
#define TNH 12    // heads
#define THD 64    // head dim
#define TNF 128   // rff features
#define KC 192    // concat K for scores (64 dot + 128 rff)

typedef __attribute__((ext_vector_type(8))) short short8;
typedef __attribute__((ext_vector_type(8))) __bf16 bf16x8;   // matches builtin signature V8y
typedef __attribute__((ext_vector_type(4))) float floatx4;

// ---------------- fp32 <-> bf16 helpers ----------------
__device__ __forceinline__ short f2bf(float x) {
    union { float f; unsigned u; } v; v.f = x;
    unsigned r = v.u + 0x7FFFu + ((v.u >> 16) & 1u);   // round-nearest-even
    return (short)(r >> 16);
}
__device__ __forceinline__ float bf2f(short x) {
    union { unsigned u; float f; } v;
    v.u = ((unsigned)(unsigned short)x) << 16;
    return v.f;
}

// ---------------- wave helpers (wave = 64) ----------------
__device__ __forceinline__ float waveReduceSum(float v) {
#pragma unroll
    for (int off = 32; off >= 1; off >>= 1) v += __shfl_xor(v, off, 64);
    return v;
}
__device__ __forceinline__ float waveReduceMax(float v) {
#pragma unroll
    for (int off = 32; off >= 1; off >>= 1) v = fmaxf(v, __shfl_xor(v, off, 64));
    return v;
}

// ---------------- fp32 inner-product microkernel (kept for small GEMMs) ----------------
__device__ __forceinline__ void fma16(float (&acc)[4][4], const float* pa, const float* pb) {
#pragma unroll
    for (int kk = 0; kk < 32; ++kk) {
        float4 a = *(const float4*)(pa + kk * 68);
        float4 b = *(const float4*)(pb + kk * 68);
        float av[4] = {a.x, a.y, a.z, a.w};
        float bv[4] = {b.x, b.y, b.z, b.w};
#pragma unroll
        for (int i = 0; i < 4; ++i)
#pragma unroll
            for (int j = 0; j < 4; ++j) acc[i][j] += av[i] * bv[j];
    }
}

// ---------------- QKV projection: Y = X @ W^T + b, scatter to (h,s,d) ----------------
// Also emits bf16 copies into the concat score operands:
//   z==0 (q): Qc[row][0:64]  = bf16(0.1125 * q)   (alpha/sqrt(HD) folded)
//   z==1 (k): Kc[row][0:64]  = bf16(k)
__global__ __launch_bounds__(256) void k_proj_qkv(
    const float* __restrict__ X,
    const float* __restrict__ W0, const float* __restrict__ b0,
    const float* __restrict__ W1, const float* __restrict__ b1,
    const float* __restrict__ W2, const float* __restrict__ b2,
    float* __restrict__ dq, float* __restrict__ dk, float* __restrict__ dv,
    short* __restrict__ Qc, short* __restrict__ Kc) {
    __shared__ float As[32][68];
    __shared__ float Bs[32][68];
    const int z = blockIdx.z;
    const float* W = (z == 0) ? W0 : ((z == 1) ? W1 : W2);
    const float* bias = (z == 0) ? b0 : ((z == 1) ? b1 : b2);
    float* dst = (z == 0) ? dq : ((z == 1) ? dk : dv);
    const int n0 = blockIdx.x * 64;
    const int m0 = blockIdx.y * 64;
    const int tid = threadIdx.x;
    float acc[4][4] = {};
    for (int k0 = 0; k0 < TH; k0 += 32) {
#pragma unroll
        for (int l = 0; l < 2; ++l) {
            int i = tid + l * 256;
            int row = i >> 3, col = (i & 7) << 2;
            float4 a = *(const float4*)&X[(m0 + row) * TH + k0 + col];
            As[col + 0][row] = a.x; As[col + 1][row] = a.y;
            As[col + 2][row] = a.z; As[col + 3][row] = a.w;
            float4 b = *(const float4*)&W[(n0 + row) * TH + k0 + col];
            Bs[col + 0][row] = b.x; Bs[col + 1][row] = b.y;
            Bs[col + 2][row] = b.z; Bs[col + 3][row] = b.w;
        }
        __syncthreads();
        fma16(acc, &As[0][0] + ((tid >> 4) << 2), &Bs[0][0] + ((tid & 15) << 2));
        __syncthreads();
    }
    const int mb = m0 + ((tid >> 4) << 2);
    const int nb = n0 + ((tid & 15) << 2);
#pragma unroll
    for (int i = 0; i < 4; ++i)
#pragma unroll
        for (int j = 0; j < 4; ++j) {
            int n = nb + j;
            float val = acc[i][j] + bias[n];
            int h = n >> 6, d = n & 63;
            int row = h * TS + (mb + i);
            dst[row * THD + d] = val;
            if (z == 0) Qc[(size_t)row * KC + d] = f2bf(val * 0.1125f);
            else if (z == 1) Kc[(size_t)row * KC + d] = f2bf(val);
        }
}

// ---------------- output projection: out = ctx @ Wo^T + bo ----------------
__global__ __launch_bounds__(256) void k_proj_out(
    const float* __restrict__ X, const float* __restrict__ W,
    const float* __restrict__ bias, float* __restrict__ out) {
    __shared__ float As[32][68];
    __shared__ float Bs[32][68];
    const int n0 = blockIdx.x * 64;
    const int m0 = blockIdx.y * 64;
    const int tid = threadIdx.x;
    float acc[4][4] = {};
    for (int k0 = 0; k0 < TH; k0 += 32) {
#pragma unroll
        for (int l = 0; l < 2; ++l) {
            int i = tid + l * 256;
            int row = i >> 3, col = (i & 7) << 2;
            float4 a = *(const float4*)&X[(m0 + row) * TH + k0 + col];
            As[col + 0][row] = a.x; As[col + 1][row] = a.y;
            As[col + 2][row] = a.z; As[col + 3][row] = a.w;
            float4 b = *(const float4*)&W[(n0 + row) * TH + k0 + col];
            Bs[col + 0][row] = b.x; Bs[col + 1][row] = b.y;
            Bs[col + 2][row] = b.z; Bs[col + 3][row] = b.w;
        }
        __syncthreads();
        fma16(acc, &As[0][0] + ((tid >> 4) << 2), &Bs[0][0] + ((tid & 15) << 2));
        __syncthreads();
    }
    const int mb = m0 + ((tid >> 4) << 2);
    const int nb = n0 + ((tid & 15) << 2);
#pragma unroll
    for (int i = 0; i < 4; ++i)
#pragma unroll
        for (int j = 0; j < 4; ++j) {
            int n = nb + j;
            out[(mb + i) * TH + n] = acc[i][j] + bias[n];
        }
}

// ---------------- row inverse norms for q,k ----------------
__global__ __launch_bounds__(64) void k_rownorm(
    const float* __restrict__ q, const float* __restrict__ kbuf,
    float* __restrict__ invq, float* __restrict__ invk) {
    const int row = blockIdx.x;
    const float* src = blockIdx.y ? kbuf : q;
    float* dst = blockIdx.y ? invk : invq;
    float x = src[row * THD + threadIdx.x];
    float ss = waveReduceSum(x * x);
    if (threadIdx.x == 0) dst[row] = 1.0f / (sqrtf(ss) + 1e-5f);
}

// ---------------- phi GEMM: Z = (x*inv) @ omega[h]^T ; write bf16(0.125*cos(Z+b)) ----------------
// Output goes straight into Qc/Kc cols [64:192] (unnormalized; k_phinorm fixes in place).
__global__ __launch_bounds__(256) void k_phi(
    const float* __restrict__ q, const float* __restrict__ kbuf,
    const float* __restrict__ invq, const float* __restrict__ invk,
    const float* __restrict__ omega, const float* __restrict__ rffb,
    short* __restrict__ Qc, short* __restrict__ Kc) {
    __shared__ float As[32][68];
    __shared__ float Bs[32][68];
    const int z = blockIdx.z;
    const int h = z >> 1, which = z & 1;
    const float* X = which ? kbuf : q;
    const float* inv = which ? invk : invq;
    short* dst = which ? Kc : Qc;
    const int n0 = blockIdx.x * 64;
    const int m0 = blockIdx.y * 64;
    const int tid = threadIdx.x;
    float acc[4][4] = {};
    for (int k0 = 0; k0 < THD; k0 += 32) {
#pragma unroll
        for (int l = 0; l < 2; ++l) {
            int i = tid + l * 256;
            int row = i >> 3, col = (i & 7) << 2;
            int rq = h * TS + m0 + row;
            float s = inv[rq];
            float4 a = *(const float4*)&X[rq * THD + k0 + col];
            As[col + 0][row] = a.x * s; As[col + 1][row] = a.y * s;
            As[col + 2][row] = a.z * s; As[col + 3][row] = a.w * s;
            float4 b = *(const float4*)&omega[(h * TNF + n0 + row) * THD + k0 + col];
            Bs[col + 0][row] = b.x; Bs[col + 1][row] = b.y;
            Bs[col + 2][row] = b.z; Bs[col + 3][row] = b.w;
        }
        __syncthreads();
        fma16(acc, &As[0][0] + ((tid >> 4) << 2), &Bs[0][0] + ((tid & 15) << 2));
        __syncthreads();
    }
    const int mb = m0 + ((tid >> 4) << 2);
    const int nb = n0 + ((tid & 15) << 2);
#pragma unroll
    for (int i = 0; i < 4; ++i)
#pragma unroll
        for (int j = 0; j < 4; ++j) {
            int f = nb + j;
            float zv = acc[i][j] + rffb[h * TNF + f];   // SIGMA = 1
            dst[(size_t)(h * TS + (mb + i)) * KC + 64 + f] = f2bf(0.125f * cosf(zv));
        }
}

// ---------------- phi row L2-normalize in place (bf16); fold (1-alpha)=0.1 into phi_q ----------------
__global__ __launch_bounds__(128) void k_phinorm(short* __restrict__ Qc, short* __restrict__ Kc) {
    const int row = blockIdx.x;
    short* buf = (blockIdx.y ? Kc : Qc) + (size_t)row * KC + 64;
    const float scale0 = blockIdx.y ? 1.0f : 0.1f;
    const int tid = threadIdx.x;
    float p = bf2f(buf[tid]);
    float ss = waveReduceSum(p * p);
    __shared__ float sh[2];
    if ((tid & 63) == 0) sh[tid >> 6] = ss;
    __syncthreads();
    ss = sh[0] + sh[1];
    float sc = scale0 / (sqrtf(ss) + 1e-6f);
    buf[tid] = f2bf(p * sc);
}

// ---------------- scores: bf16 MFMA concat-K GEMM (K = 192), 128x128 tile, 4 waves ----------------
__global__ __launch_bounds__(256) void k_scores_mfma(
    const short* __restrict__ Qc, const short* __restrict__ Kc,
    const float* __restrict__ mask, float* __restrict__ wout) {
    __shared__ __align__(16) short Asb[128][40];   // 80 B row stride: 16B-aligned, <=2-way bank alias
    __shared__ __align__(16) short Bsb[128][40];
    const int h = blockIdx.z;
    const int n0 = blockIdx.x * 128;
    const int m0 = blockIdx.y * 128;
    const int tid = threadIdx.x;
    const int lane = tid & 63;
    const int w = tid >> 6;
    const int wm = (w >> 1) * 64, wn = (w & 1) * 64;
    const int fr = lane & 15;          // fragment row/col within 16
    const int quad = lane >> 4;        // k-quad

    floatx4 acc[4][4] = {};

    for (int k0 = 0; k0 < KC; k0 += 32) {
#pragma unroll
        for (int l = 0; l < 2; ++l) {
            int c = tid + l * 256;
            int row = c >> 2, col = (c & 3) << 3;
            short8 a = *(const short8*)&Qc[(size_t)(h * TS + m0 + row) * KC + k0 + col];
            *(short8*)&Asb[row][col] = a;
            short8 b = *(const short8*)&Kc[(size_t)(h * TS + n0 + row) * KC + k0 + col];
            *(short8*)&Bsb[row][col] = b;
        }
        __syncthreads();
        bf16x8 af[4], bfr[4];
#pragma unroll
        for (int i = 0; i < 4; ++i) af[i] = *(const bf16x8*)&Asb[wm + i * 16 + fr][quad * 8];
#pragma unroll
        for (int j = 0; j < 4; ++j) bfr[j] = *(const bf16x8*)&Bsb[wn + j * 16 + fr][quad * 8];
#pragma unroll
        for (int i = 0; i < 4; ++i)
#pragma unroll
            for (int j = 0; j < 4; ++j)
                acc[i][j] = __builtin_amdgcn_mfma_f32_16x16x32_bf16(af[i], bfr[j], acc[i][j], 0, 0, 0);
        __syncthreads();
    }
    // epilogue: C/D layout col=lane&15, row=(lane>>4)*4+reg
#pragma unroll
    for (int j = 0; j < 4; ++j) {
        int col_g = n0 + wn + j * 16 + fr;
        float mb = (mask[col_g] - 1.0f) * 10000.0f;
#pragma unroll
        for (int i = 0; i < 4; ++i) {
#pragma unroll
            for (int r = 0; r < 4; ++r) {
                int row_g = m0 + wm + i * 16 + quad * 4 + r;
                wout[(size_t)(h * TS + row_g) * TS + col_g] = acc[i][j][r] + mb;
            }
        }
    }
}

// ---------------- softmax over rows of 2048, in place ----------------
__global__ __launch_bounds__(256) void k_softmax(float* __restrict__ wout) {
    const int row = blockIdx.x;
    float4* p = (float4*)(wout + (size_t)row * TS);
    const int tid = threadIdx.x;
    float4 x0 = p[tid], x1 = p[tid + 256];
    float mx = fmaxf(fmaxf(fmaxf(x0.x, x0.y), fmaxf(x0.z, x0.w)),
                     fmaxf(fmaxf(x1.x, x1.y), fmaxf(x1.z, x1.w)));
    mx = waveReduceMax(mx);
    __shared__ float rm[4];
    __shared__ float rs[4];
    if ((tid & 63) == 0) rm[tid >> 6] = mx;
    __syncthreads();
    mx = fmaxf(fmaxf(rm[0], rm[1]), fmaxf(rm[2], rm[3]));
    float e[8];
    e[0] = __expf(x0.x - mx); e[1] = __expf(x0.y - mx);
    e[2] = __expf(x0.z - mx); e[3] = __expf(x0.w - mx);
    e[4] = __expf(x1.x - mx); e[5] = __expf(x1.y - mx);
    e[6] = __expf(x1.z - mx); e[7] = __expf(x1.w - mx);
    float sum = ((e[0] + e[1]) + (e[2] + e[3])) + ((e[4] + e[5]) + (e[6] + e[7]));
    sum = waveReduceSum(sum);
    if ((tid & 63) == 0) rs[tid >> 6] = sum;
    __syncthreads();
    sum = rs[0] + rs[1] + rs[2] + rs[3];
    float rinv = 1.0f / sum;
    x0.x = e[0] * rinv; x0.y = e[1] * rinv; x0.z = e[2] * rinv; x0.w = e[3] * rinv;
    x1.x = e[4] * rinv; x1.y = e[5] * rinv; x1.z = e[6] * rinv; x1.w = e[7] * rinv;
    p[tid] = x0;
    p[tid + 256] = x1;
}

// ---------------- context GEMM: ctx[s, h*64+d] = sum_t w[h,s,t] * v[h,t,d] ----------------
__global__ __launch_bounds__(256) void k_ctx(
    const float* __restrict__ wout, const float* __restrict__ v, float* __restrict__ ctx) {
    __shared__ float As[32][68];
    __shared__ float Bs[32][68];
    const int h = blockIdx.y;
    const int m0 = blockIdx.x * 64;
    const int tid = threadIdx.x;
    float acc[4][4] = {};
    for (int k0 = 0; k0 < TS; k0 += 32) {
#pragma unroll
        for (int l = 0; l < 2; ++l) {
            int i = tid + l * 256;
            {
                int row = i >> 3, col = (i & 7) << 2;
                float4 a = *(const float4*)&wout[(size_t)(h * TS + m0 + row) * TS + k0 + col];
                As[col + 0][row] = a.x; As[col + 1][row] = a.y;
                As[col + 2][row] = a.z; As[col + 3][row] = a.w;
            }
            {
                int row = i >> 4, col = (i & 15) << 2;
                float4 b = *(const float4*)&v[(h * TS + k0 + row) * THD + col];
                *(float4*)&Bs[row][col] = b;
            }
        }
        __syncthreads();
        fma16(acc, &As[0][0] + ((tid >> 4) << 2), &Bs[0][0] + ((tid & 15) << 2));
        __syncthreads();
    }
    const int mb = m0 + ((tid >> 4) << 2);
    const int nb = (tid & 15) << 2;
#pragma unroll
    for (int i = 0; i < 4; ++i)
#pragma unroll
        for (int j = 0; j < 4; ++j) {
            ctx[(mb + i) * TH + h * THD + (nb + j)] = acc[i][j];
        }
}

extern "C" void kernel_launch(void* const* d_in, const int* in_sizes, int n_in,
                              void* d_out, int out_size, void* d_ws, size_t ws_size,
                              hipStream_t stream) {
    const float* hs    = (const float*)d_in[0];
    const float* mask  = (const float*)d_in[1];
    const float* Wq    = (const float*)d_in[2];
    const float* bq    = (const float*)d_in[3];
    const float* Wk    = (const float*)d_in[4];
    const float* bk    = (const float*)d_in[5];
    const float* Wv    = (const float*)d_in[6];
    const float* bv    = (const float*)d_in[7];
    const float* Wo    = (const float*)d_in[8];
    const float* bo    = (const float*)d_in[9];
    const float* omega = (const float*)d_in[10];
    const float* rffb  = (const float*)d_in[11];

    float* out0 = (float*)d_out;               // (S,H) final output
    float* wout = out0 + TS * TH;              // (NH,S,S) attention weights

    // workspace layout (floats); total ~11.06M floats = ~44.2 MB
    float* ws   = (float*)d_ws;
    float* q    = ws;                          // NH*S*HD = 1572864
    float* kbuf = ws + 1572864;
    float* v    = ws + 3145728;
    float* invq = ws + 4718592;                // NH*S = 24576
    float* invk = ws + 4743168;
    float* ctx  = ws + 4767744;                // S*H = 1572864
    short* Qc   = (short*)(ws + 6340608);      // NH*S*KC bf16 = 4718592 shorts
    short* Kc   = (short*)(ws + 8699904);

    k_proj_qkv<<<dim3(12, 32, 3), 256, 0, stream>>>(hs, Wq, bq, Wk, bk, Wv, bv, q, kbuf, v, Qc, Kc);
    k_rownorm<<<dim3(TNH * TS, 2), 64, 0, stream>>>(q, kbuf, invq, invk);
    k_phi<<<dim3(2, 32, 24), 256, 0, stream>>>(q, kbuf, invq, invk, omega, rffb, Qc, Kc);
    k_phinorm<<<dim3(TNH * TS, 2), 128, 0, stream>>>(Qc, Kc);
    k_scores_mfma<<<dim3(16, 16, 12), 256, 0, stream>>>(Qc, Kc, mask, wout);
    k_softmax<<<TNH * TS, 256, 0, stream>>>(wout);
    k_ctx<<<dim3(32, 12), 256, 0, stream>>>(wout, v, ctx);
    k_proj_out<<<dim3(12, 32), 256, 0, stream>>>(ctx, Wo, bo, out0);
}